// Round 13
// baseline (239.858 us; speedup 1.0000x reference)
//
#include <hip/hip_runtime.h>

typedef __attribute__((ext_vector_type(8))) short short8;
typedef __attribute__((ext_vector_type(4))) float f32x4;
typedef __attribute__((ext_vector_type(16))) float f32x16;
typedef unsigned short u16;
typedef unsigned int u32;

#define NB 4
#define CH 128
#define INTER2 64
#define HW2 9216
#define NN 4608
#define NSLICE 16
#define SLW2 288
#define PCH 136   // xT LDS pitch (u16)
#define APITCH 136

#if __has_builtin(__builtin_amdgcn_exp2f)
#define EXP2F __builtin_amdgcn_exp2f
#else
#define EXP2F exp2f
#endif

__device__ __forceinline__ u16 f2bf(float f) {
  u32 u = __float_as_uint(f);
  u += 0x7fffu + ((u >> 16) & 1u);
  return (u16)(u >> 16);
}
__device__ __forceinline__ float bf2f(u16 h) { return __uint_as_float(((u32)h) << 16); }
__device__ __forceinline__ u32 cvtpk(float lo, float hi) {
  u32 r;
  asm("v_cvt_pk_bf16_f32 %0, %1, %2" : "=v"(r) : "v"(lo), "v"(hi));
  return r;
}

// ---------------- K0: all weights f32 -> bf16 ----------------
__global__ void k_wcvt(const float* __restrict__ wt, const float* __restrict__ wp,
                       const float* __restrict__ wg, const float* __restrict__ wm,
                       u16* __restrict__ wtb, u16* __restrict__ wpb,
                       u16* __restrict__ wgb, u16* __restrict__ wmb) {
  int i = blockIdx.x * 256 + threadIdx.x;
  if (i < CH * INTER2) {
    wtb[i] = f2bf(wt[i]);
    wpb[i] = f2bf(wp[i]);
    wgb[i] = f2bf(wg[i]);
    wmb[i] = f2bf(wm[i]);
  }
}

// ---------------- K1: fused conv GEMM (unchanged, proven) ----------------
__global__ __launch_bounds__(256) void k_conv(const float* __restrict__ x1,
                                              const float* __restrict__ x2,
                                              const u16* __restrict__ wtb,
                                              const u16* __restrict__ wpb,
                                              const u16* __restrict__ wgb,
                                              u16* __restrict__ Tt,
                                              u16* __restrict__ Pt,
                                              u16* __restrict__ Gn) {
  __shared__ u16 xT[64 * PCH];
  __shared__ u16 ot[64 * 72];
  const int tid = threadIdx.x;
  const int w = tid >> 6, l = tid & 63, lr = l & 15, lg = l >> 4;
  const int pt = blockIdx.x, b = blockIdx.y, z = blockIdx.z;
  const int p0 = pt * 64;
  const int h = (p0 >= NN) ? 1 : 0;
  const int n0 = p0 - h * NN;
  const float* X = (z ? x2 : x1) + (size_t)b * CH * HW2;

  {
    const int pq = (l & 15) * 4;
    const int cs = w + 4 * (l >> 4);
#pragma unroll
    for (int it = 0; it < 8; it++) {
      const int c = it * 16 + cs;
      float4 v = *(const float4*)(X + (size_t)c * HW2 + p0 + pq);
      xT[(pq + 0) * PCH + c] = f2bf(v.x);
      xT[(pq + 1) * PCH + c] = f2bf(v.y);
      xT[(pq + 2) * PCH + c] = f2bf(v.z);
      xT[(pq + 3) * PCH + c] = f2bf(v.w);
    }
  }
  short8 wsP[4], wsG[4];
  {
    const u16* W1 = z ? wpb : wtb;
#pragma unroll
    for (int ks = 0; ks < 4; ks++)
      wsP[ks] = *(const short8*)(W1 + (w * 16 + lr) * CH + ks * 32 + lg * 8);
    if (z) {
#pragma unroll
      for (int ks = 0; ks < 4; ks++)
        wsG[ks] = *(const short8*)(wgb + (w * 16 + lr) * CH + ks * 32 + lg * 8);
    }
  }
  __syncthreads();
  short8 xf[4][4];
#pragma unroll
  for (int tp = 0; tp < 4; tp++)
#pragma unroll
    for (int ks = 0; ks < 4; ks++)
      xf[tp][ks] = *(const short8*)(&xT[(tp * 16 + lr) * PCH + ks * 32 + lg * 8]);

  f32x4 accP[4];
#pragma unroll
  for (int tp = 0; tp < 4; tp++) {
#pragma unroll
    for (int j = 0; j < 4; j++) accP[tp][j] = 0.f;
#pragma unroll
    for (int ks = 0; ks < 4; ks++)
      accP[tp] = __builtin_amdgcn_mfma_f32_16x16x32_bf16(xf[tp][ks], wsP[ks], accP[tp], 0, 0, 0);
  }
#pragma unroll
  for (int tp = 0; tp < 4; tp++) {
#pragma unroll
    for (int j = 0; j < 4; j++)
      ot[(tp * 16 + lg * 4 + j) * 72 + w * 16 + lr] = f2bf(accP[tp][j]);
  }
  if (z) {
    f32x4 accG[4];
#pragma unroll
    for (int tp = 0; tp < 4; tp++) {
#pragma unroll
      for (int j = 0; j < 4; j++) accG[tp][j] = 0.f;
#pragma unroll
      for (int ks = 0; ks < 4; ks++)
        accG[tp] = __builtin_amdgcn_mfma_f32_16x16x32_bf16(wsG[ks], xf[tp][ks], accG[tp], 0, 0, 0);
    }
    u16* Gb = Gn + (size_t)b * CH * NN;
#pragma unroll
    for (int tp = 0; tp < 4; tp++) {
#pragma unroll
      for (int j = 0; j < 4; j++) {
        const int ig = w * 16 + lg * 4 + j;
        Gb[(size_t)((h << 6) + ig) * NN + n0 + tp * 16 + lr] = f2bf(accG[tp][j]);
      }
    }
  }
  __syncthreads();
  {
    u16* dst = (z ? Pt : Tt) + (size_t)b * NN * CH;
#pragma unroll
    for (int q = 0; q < 2; q++) {
      const int idx = tid * 2 + q;
      const int p = idx >> 3, c8 = (idx & 7) * 8;
      uint4 v = *(const uint4*)(&ot[p * 72 + c8]);
      *(uint4*)(dst + (size_t)(n0 + p) * CH + h * 64 + c8) = v;
    }
  }
}

// ---------------- K2: den-only pass. m-tile 256 resident, 16 n-slices ----------------
__global__ __launch_bounds__(256) void k_den(const u16* __restrict__ Tt,
                                             const u16* __restrict__ Pt,
                                             float* __restrict__ denp) {
  const int tid = threadIdx.x;
  const int w = tid >> 6, l = tid & 63, lm = l & 31, lh = l >> 5;
  const int s = blockIdx.x & 15, mt = blockIdx.x >> 4;
  const int b = blockIdx.y;
  const int m0 = mt * 256;
  const int nbase = s * SLW2;
  const u16* PtB = Pt + (size_t)b * NN * CH;
  const u16* TtB = Tt + (size_t)b * NN * CH;

  short8 bf[2][8];
#pragma unroll
  for (int ms = 0; ms < 2; ms++)
#pragma unroll
    for (int ks = 0; ks < 8; ks++)
      bf[ms][ks] = *(const short8*)(PtB + (size_t)(m0 + w * 64 + ms * 32 + lm) * CH + ks * 16 + lh * 8);

  float den0 = 0.f, den1 = 0.f;
  short8 ac[8], an[8];
#pragma unroll
  for (int ks = 0; ks < 8; ks++)
    ac[ks] = *(const short8*)(TtB + (size_t)(nbase + lm) * CH + ks * 16 + lh * 8);

  for (int it = 0; it < 9; it++) {
    if (it + 1 < 9) {
      const int nr = nbase + (it + 1) * 32 + lm;
#pragma unroll
      for (int ks = 0; ks < 8; ks++)
        an[ks] = *(const short8*)(TtB + (size_t)nr * CH + ks * 16 + lh * 8);
    }
    f32x16 a0, a1;
#pragma unroll
    for (int q = 0; q < 16; q++) { a0[q] = 0.f; a1[q] = 0.f; }
#pragma unroll
    for (int ks = 0; ks < 8; ks++) {
      a0 = __builtin_amdgcn_mfma_f32_32x32x16_bf16(ac[ks], bf[0][ks], a0, 0, 0, 0);
      a1 = __builtin_amdgcn_mfma_f32_32x32x16_bf16(ac[ks], bf[1][ks], a1, 0, 0, 0);
    }
#pragma unroll
    for (int q = 0; q < 16; q++) {
      den0 += EXP2F(__builtin_fmaf(a0[q], 1.44269504f, -57.70780163f));
      den1 += EXP2F(__builtin_fmaf(a1[q], 1.44269504f, -57.70780163f));
    }
    if (it + 1 < 9) {
#pragma unroll
      for (int ks = 0; ks < 8; ks++) ac[ks] = an[ks];
    }
  }
  den0 += __shfl_xor(den0, 32, 64);
  den1 += __shfl_xor(den1, 32, 64);
  if (l < 32) {
    float* dp = denp + (size_t)(s * NB + b) * NN + m0 + w * 64;
    dp[lm] = den0;
    dp[32 + lm] = den1;
  }
}

// ---------------- K2b: rdn[b][m] = 1 / sum_s denp ----------------
__global__ __launch_bounds__(256) void k_rdn(const float* __restrict__ denp,
                                             float* __restrict__ rdn) {
  const int i = blockIdx.x * 256 + threadIdx.x;
  const int b = i / NN, m = i % NN;
  float s = 0.f;
#pragma unroll
  for (int s2 = 0; s2 < NSLICE; s2++) s += denp[(size_t)(s2 * NB + b) * NN + m];
  rdn[i] = 1.0f / s;
}

// ---------------- K3: fused scores+softmax+PV -> Yp slabs (no TtS: 34.8KB LDS, 4 blocks/CU) ----------------
// grid 576: xcd=x&7, rr=x>>3, nt=rr>>1, combo c=xcd+8*(rr&1): b=c>>2, sk=c&3
__global__ __launch_bounds__(256) void k_att(const u16* __restrict__ Tt,
                                             const u16* __restrict__ Pt,
                                             const u16* __restrict__ Gn,
                                             const float* __restrict__ rdn,
                                             float* __restrict__ Yp) {
  __shared__ u16 Atile[128 * APITCH];  // [n][m] pitch 136, ~34.8 KB — only LDS
  const int tid = threadIdx.x;
  const int w = tid >> 6, l = tid & 63, lr = l & 15, lg = l >> 4;
  const int lm = l & 31, lh = l >> 5;
  const int x = blockIdx.x;
  const int xcd = x & 7, rr = x >> 3;
  const int nt = rr >> 1;
  const int c = xcd + 8 * (rr & 1);
  const int b = c >> 2, sk = c & 3;
  const int n0 = nt * 128;
  const int mbase = sk * 1152;
  const u16* TtB = Tt + (size_t)b * NN * CH;
  const u16* PtB = Pt + (size_t)b * NN * CH;
  const u16* GnB = Gn + (size_t)b * CH * NN;
  const float* rdnB = rdn + b * NN;

  const int wc = w >> 1, wn = w & 1;
  f32x4 acc[4][4];
#pragma unroll
  for (int fa = 0; fa < 4; fa++)
#pragma unroll
    for (int fb = 0; fb < 4; fb++)
#pragma unroll
      for (int j = 0; j < 4; j++) acc[fa][fb][j] = 0.f;

  for (int ch = 0; ch < 9; ch++) {
    const int mch = mbase + ch * 128;
    // ---- score phase: wave w owns m-sub w (32 m), all 128 n; af from global (L2-resident) ----
    short8 bf[8];
#pragma unroll
    for (int ks = 0; ks < 8; ks++)
      bf[ks] = *(const short8*)(PtB + (size_t)(mch + w * 32 + lm) * CH + ks * 16 + lh * 8);
    const float rv = rdnB[mch + w * 32 + lm];
#pragma unroll
    for (int ns = 0; ns < 4; ns++) {
      short8 af[8];
#pragma unroll
      for (int ks = 0; ks < 8; ks++)
        af[ks] = *(const short8*)(TtB + (size_t)(n0 + ns * 32 + lm) * CH + ks * 16 + lh * 8);
      f32x16 sa;
#pragma unroll
      for (int q = 0; q < 16; q++) sa[q] = 0.f;
#pragma unroll
      for (int ks = 0; ks < 8; ks++)
        sa = __builtin_amdgcn_mfma_f32_32x32x16_bf16(af[ks], bf[ks], sa, 0, 0, 0);
#pragma unroll
      for (int q = 0; q < 16; q += 2) {
        const int nl = ns * 32 + (q & 3) + 8 * (q >> 2) + 4 * lh;
        float e0 = EXP2F(__builtin_fmaf(sa[q], 1.44269504f, -57.70780163f)) * rv;
        float e1 = EXP2F(__builtin_fmaf(sa[q + 1], 1.44269504f, -57.70780163f)) * rv;
        u32 pk = cvtpk(e0, e1);
        Atile[nl * APITCH + w * 32 + lm] = (u16)pk;
        Atile[(nl + 1) * APITCH + w * 32 + lm] = (u16)(pk >> 16);
      }
    }
    // issue PV ks=0 gf loads before the barrier (latency hides under barrier wait)
    short8 gfc[4], gfn2[4];
#pragma unroll
    for (int fa = 0; fa < 4; fa++)
      gfc[fa] = *(const short8*)(GnB + (size_t)(wc * 64 + fa * 16 + lr) * NN + mch + lg * 8);
    __syncthreads();
    // ---- PV phase: wave (wc,wn): c-half, n-half; K = 128 m; gf one-ks-ahead ----
#pragma unroll
    for (int ks = 0; ks < 4; ks++) {
      if (ks + 1 < 4) {
#pragma unroll
        for (int fa = 0; fa < 4; fa++)
          gfn2[fa] = *(const short8*)(GnB + (size_t)(wc * 64 + fa * 16 + lr) * NN + mch + (ks + 1) * 32 + lg * 8);
      }
      short8 pb[4];
#pragma unroll
      for (int fb = 0; fb < 4; fb++)
        pb[fb] = *(const short8*)(&Atile[(wn * 64 + fb * 16 + lr) * APITCH + ks * 32 + lg * 8]);
#pragma unroll
      for (int fa = 0; fa < 4; fa++)
#pragma unroll
        for (int fb = 0; fb < 4; fb++)
          acc[fa][fb] = __builtin_amdgcn_mfma_f32_16x16x32_bf16(gfc[fa], pb[fb], acc[fa][fb], 0, 0, 0);
      if (ks + 1 < 4) {
#pragma unroll
        for (int fa = 0; fa < 4; fa++) gfc[fa] = gfn2[fa];
      }
    }
    __syncthreads();
  }
  // epilogue: write Yp slab (f32)
  float* Yb = Yp + (size_t)(sk * NB + b) * CH * NN;
#pragma unroll
  for (int fa = 0; fa < 4; fa++) {
#pragma unroll
    for (int fb = 0; fb < 4; fb++) {
      const int n = n0 + wn * 64 + fb * 16 + lr;
#pragma unroll
      for (int j = 0; j < 4; j++) {
        const int d = wc * 64 + fa * 16 + lg * 4 + j;
        Yb[(size_t)d * NN + n] = acc[fa][fb][j];
      }
    }
  }
}

// ---------------- K4: reduce Yp over 4 sk-slabs, mask-GEMM + residual ----------------
__global__ __launch_bounds__(256) void k_out(const float* __restrict__ Yp,
                                             const u16* __restrict__ wmb,
                                             const float* __restrict__ x1,
                                             float* __restrict__ out) {
  __shared__ u16 yy[64][72];
  const int tid = threadIdx.x;
  const int w = tid >> 6, l = tid & 63, lr = l & 15, lg = l >> 4;
  const int b = blockIdx.y;
  const int n0 = blockIdx.x * 32;
  const int nl = tid & 31, cch = tid >> 5;

  float v[16];
#pragma unroll
  for (int q = 0; q < 16; q++) v[q] = 0.f;
#pragma unroll
  for (int s2 = 0; s2 < 4; s2++) {
    const float* base = Yp + ((size_t)(s2 * NB + b) * CH + cch * 16) * NN + n0 + nl;
#pragma unroll
    for (int q = 0; q < 16; q++) v[q] += base[(size_t)q * NN];
  }
#pragma unroll
  for (int q = 0; q < 16; q++) {
    const int d = cch * 16 + q;  // d = h*64 + i
    yy[(d >> 6) * 32 + nl][d & 63] = f2bf(v[q]);
  }
  __syncthreads();

  const int wm3 = w >> 1, wp3 = w & 1;
  f32x4 eacc[4][2];
#pragma unroll
  for (int fa = 0; fa < 4; fa++)
#pragma unroll
    for (int fb = 0; fb < 2; fb++)
#pragma unroll
      for (int j = 0; j < 4; j++) eacc[fa][fb][j] = 0.f;
#pragma unroll
  for (int ks = 0; ks < 2; ks++) {
    short8 wa[4];
#pragma unroll
    for (int fa = 0; fa < 4; fa++)
      wa[fa] = *(const short8*)(wmb + (wm3 * 64 + fa * 16 + lr) * 64 + ks * 32 + lg * 8);
    short8 yb[2];
#pragma unroll
    for (int fb = 0; fb < 2; fb++)
      yb[fb] = *(const short8*)(&yy[wp3 * 32 + fb * 16 + lr][ks * 32 + lg * 8]);
#pragma unroll
    for (int fa = 0; fa < 4; fa++)
#pragma unroll
      for (int fb = 0; fb < 2; fb++)
        eacc[fa][fb] = __builtin_amdgcn_mfma_f32_16x16x32_bf16(wa[fa], yb[fb], eacc[fa][fb], 0, 0, 0);
  }
  const float* x1b = x1 + (size_t)b * CH * HW2;
  float* ob = out + (size_t)b * CH * HW2;
#pragma unroll
  for (int fa = 0; fa < 4; fa++) {
#pragma unroll
    for (int fb = 0; fb < 2; fb++) {
      const int pl = wp3 * 32 + fb * 16 + lr;
      const int col = n0 + (pl & 31) + (pl >> 5) * NN;
#pragma unroll
      for (int j = 0; j < 4; j++) {
        const int c = wm3 * 64 + fa * 16 + lg * 4 + j;
        const size_t o = (size_t)c * HW2 + col;
        ob[o] = eacc[fa][fb][j] + x1b[o];
      }
    }
  }
}

extern "C" void kernel_launch(void* const* d_in, const int* in_sizes, int n_in,
                              void* d_out, int out_size, void* d_ws, size_t ws_size,
                              hipStream_t stream) {
  const float* x1 = (const float*)d_in[0];
  const float* x2 = (const float*)d_in[1];
  const float* wt = (const float*)d_in[2];
  const float* wp = (const float*)d_in[3];
  const float* wg = (const float*)d_in[4];
  const float* wm = (const float*)d_in[5];
  float* out = (float*)d_out;

  char* ws = (char*)d_ws;
  const size_t SZ_T = (size_t)NB * NN * CH * 2;
  u16* Tt = (u16*)ws; ws += SZ_T;
  u16* Pt = (u16*)ws; ws += SZ_T;
  u16* Gn = (u16*)ws; ws += SZ_T;
  float* denp = (float*)ws; ws += (size_t)NSLICE * NB * NN * 4;
  float* rdn = (float*)ws; ws += (size_t)NB * NN * 4;
  u16* wtb = (u16*)ws; ws += (size_t)CH * INTER2 * 2;
  u16* wpb = (u16*)ws; ws += (size_t)CH * INTER2 * 2;
  u16* wgb = (u16*)ws; ws += (size_t)CH * INTER2 * 2;
  u16* wmb = (u16*)ws; ws += (size_t)CH * INTER2 * 2;
  float* Yp = (float*)ws; ws += (size_t)16 * CH * NN * 4;
  if (ws_size < (size_t)(ws - (char*)d_ws)) return;

  hipLaunchKernelGGL(k_wcvt, dim3(32), dim3(256), 0, stream, wt, wp, wg, wm, wtb, wpb, wgb, wmb);
  hipLaunchKernelGGL(k_conv, dim3(144, NB, 2), dim3(256), 0, stream, x1, x2, wtb, wpb, wgb, Tt, Pt, Gn);
  hipLaunchKernelGGL(k_den, dim3(288, NB), dim3(256), 0, stream, Tt, Pt, denp);
  hipLaunchKernelGGL(k_rdn, dim3(72), dim3(256), 0, stream, denp, rdn);
  hipLaunchKernelGGL(k_att, dim3(576), dim3(256), 0, stream, Tt, Pt, Gn, rdn, Yp);
  hipLaunchKernelGGL(k_out, dim3(144, NB), dim3(256), 0, stream, Yp, wmb, x1, out);
}

// Round 14
// 219.206 us; speedup vs baseline: 1.0942x; 1.0942x over previous
//
#include <hip/hip_runtime.h>

typedef __attribute__((ext_vector_type(8))) short short8;
typedef __attribute__((ext_vector_type(4))) float f32x4;
typedef __attribute__((ext_vector_type(16))) float f32x16;
typedef unsigned short u16;
typedef unsigned int u32;

#define NB 4
#define CH 128
#define INTER2 64
#define HW2 9216
#define NN 4608
#define NSLICE 16
#define SLW2 288
#define PCH 136   // xT LDS pitch (u16)

#if __has_builtin(__builtin_amdgcn_exp2f)
#define EXP2F __builtin_amdgcn_exp2f
#else
#define EXP2F exp2f
#endif

__device__ __forceinline__ u16 f2bf(float f) {
  u32 u = __float_as_uint(f);
  u += 0x7fffu + ((u >> 16) & 1u);
  return (u16)(u >> 16);
}
__device__ __forceinline__ float bf2f(u16 h) { return __uint_as_float(((u32)h) << 16); }
__device__ __forceinline__ u32 cvtpk(float lo, float hi) {
  u32 r;
  asm("v_cvt_pk_bf16_f32 %0, %1, %2" : "=v"(r) : "v"(lo), "v"(hi));
  return r;
}
__device__ __forceinline__ void gl_lds16(const u16* g, u16* l) {
  __builtin_amdgcn_global_load_lds(
      (const __attribute__((address_space(1))) unsigned int*)g,
      (__attribute__((address_space(3))) unsigned int*)l, 16, 0, 0);
}

// ---------------- K0: all weights f32 -> bf16 ----------------
__global__ void k_wcvt(const float* __restrict__ wt, const float* __restrict__ wp,
                       const float* __restrict__ wg, const float* __restrict__ wm,
                       u16* __restrict__ wtb, u16* __restrict__ wpb,
                       u16* __restrict__ wgb, u16* __restrict__ wmb) {
  int i = blockIdx.x * 256 + threadIdx.x;
  if (i < CH * INTER2) {
    wtb[i] = f2bf(wt[i]);
    wpb[i] = f2bf(wp[i]);
    wgb[i] = f2bf(wg[i]);
    wmb[i] = f2bf(wm[i]);
  }
}

// ---------------- K1: fused conv GEMM (unchanged, proven) ----------------
__global__ __launch_bounds__(256) void k_conv(const float* __restrict__ x1,
                                              const float* __restrict__ x2,
                                              const u16* __restrict__ wtb,
                                              const u16* __restrict__ wpb,
                                              const u16* __restrict__ wgb,
                                              u16* __restrict__ Tt,
                                              u16* __restrict__ Pt,
                                              u16* __restrict__ Gn) {
  __shared__ u16 xT[64 * PCH];
  __shared__ u16 ot[64 * 72];
  const int tid = threadIdx.x;
  const int w = tid >> 6, l = tid & 63, lr = l & 15, lg = l >> 4;
  const int pt = blockIdx.x, b = blockIdx.y, z = blockIdx.z;
  const int p0 = pt * 64;
  const int h = (p0 >= NN) ? 1 : 0;
  const int n0 = p0 - h * NN;
  const float* X = (z ? x2 : x1) + (size_t)b * CH * HW2;

  {
    const int pq = (l & 15) * 4;
    const int cs = w + 4 * (l >> 4);
#pragma unroll
    for (int it = 0; it < 8; it++) {
      const int c = it * 16 + cs;
      float4 v = *(const float4*)(X + (size_t)c * HW2 + p0 + pq);
      xT[(pq + 0) * PCH + c] = f2bf(v.x);
      xT[(pq + 1) * PCH + c] = f2bf(v.y);
      xT[(pq + 2) * PCH + c] = f2bf(v.z);
      xT[(pq + 3) * PCH + c] = f2bf(v.w);
    }
  }
  short8 wsP[4], wsG[4];
  {
    const u16* W1 = z ? wpb : wtb;
#pragma unroll
    for (int ks = 0; ks < 4; ks++)
      wsP[ks] = *(const short8*)(W1 + (w * 16 + lr) * CH + ks * 32 + lg * 8);
    if (z) {
#pragma unroll
      for (int ks = 0; ks < 4; ks++)
        wsG[ks] = *(const short8*)(wgb + (w * 16 + lr) * CH + ks * 32 + lg * 8);
    }
  }
  __syncthreads();
  short8 xf[4][4];
#pragma unroll
  for (int tp = 0; tp < 4; tp++)
#pragma unroll
    for (int ks = 0; ks < 4; ks++)
      xf[tp][ks] = *(const short8*)(&xT[(tp * 16 + lr) * PCH + ks * 32 + lg * 8]);

  f32x4 accP[4];
#pragma unroll
  for (int tp = 0; tp < 4; tp++) {
#pragma unroll
    for (int j = 0; j < 4; j++) accP[tp][j] = 0.f;
#pragma unroll
    for (int ks = 0; ks < 4; ks++)
      accP[tp] = __builtin_amdgcn_mfma_f32_16x16x32_bf16(xf[tp][ks], wsP[ks], accP[tp], 0, 0, 0);
  }
#pragma unroll
  for (int tp = 0; tp < 4; tp++) {
#pragma unroll
    for (int j = 0; j < 4; j++)
      ot[(tp * 16 + lg * 4 + j) * 72 + w * 16 + lr] = f2bf(accP[tp][j]);
  }
  if (z) {
    f32x4 accG[4];
#pragma unroll
    for (int tp = 0; tp < 4; tp++) {
#pragma unroll
      for (int j = 0; j < 4; j++) accG[tp][j] = 0.f;
#pragma unroll
      for (int ks = 0; ks < 4; ks++)
        accG[tp] = __builtin_amdgcn_mfma_f32_16x16x32_bf16(wsG[ks], xf[tp][ks], accG[tp], 0, 0, 0);
    }
    u16* Gb = Gn + (size_t)b * CH * NN;
#pragma unroll
    for (int tp = 0; tp < 4; tp++) {
#pragma unroll
      for (int j = 0; j < 4; j++) {
        const int ig = w * 16 + lg * 4 + j;
        Gb[(size_t)((h << 6) + ig) * NN + n0 + tp * 16 + lr] = f2bf(accG[tp][j]);
      }
    }
  }
  __syncthreads();
  {
    u16* dst = (z ? Pt : Tt) + (size_t)b * NN * CH;
#pragma unroll
    for (int q = 0; q < 2; q++) {
      const int idx = tid * 2 + q;
      const int p = idx >> 3, c8 = (idx & 7) * 8;
      uint4 v = *(const uint4*)(&ot[p * 72 + c8]);
      *(uint4*)(dst + (size_t)(n0 + p) * CH + h * 64 + c8) = v;
    }
  }
}

// ---------------- K2: den-only pass. m-tile 256 resident, 16 n-slices ----------------
__global__ __launch_bounds__(256) void k_den(const u16* __restrict__ Tt,
                                             const u16* __restrict__ Pt,
                                             float* __restrict__ denp) {
  const int tid = threadIdx.x;
  const int w = tid >> 6, l = tid & 63, lm = l & 31, lh = l >> 5;
  const int s = blockIdx.x & 15, mt = blockIdx.x >> 4;
  const int b = blockIdx.y;
  const int m0 = mt * 256;
  const int nbase = s * SLW2;
  const u16* PtB = Pt + (size_t)b * NN * CH;
  const u16* TtB = Tt + (size_t)b * NN * CH;

  short8 bf[2][8];
#pragma unroll
  for (int ms = 0; ms < 2; ms++)
#pragma unroll
    for (int ks = 0; ks < 8; ks++)
      bf[ms][ks] = *(const short8*)(PtB + (size_t)(m0 + w * 64 + ms * 32 + lm) * CH + ks * 16 + lh * 8);

  float den0 = 0.f, den1 = 0.f;
  short8 ac[8], an[8];
#pragma unroll
  for (int ks = 0; ks < 8; ks++)
    ac[ks] = *(const short8*)(TtB + (size_t)(nbase + lm) * CH + ks * 16 + lh * 8);

  for (int it = 0; it < 9; it++) {
    if (it + 1 < 9) {
      const int nr = nbase + (it + 1) * 32 + lm;
#pragma unroll
      for (int ks = 0; ks < 8; ks++)
        an[ks] = *(const short8*)(TtB + (size_t)nr * CH + ks * 16 + lh * 8);
    }
    f32x16 a0, a1;
#pragma unroll
    for (int q = 0; q < 16; q++) { a0[q] = 0.f; a1[q] = 0.f; }
#pragma unroll
    for (int ks = 0; ks < 8; ks++) {
      a0 = __builtin_amdgcn_mfma_f32_32x32x16_bf16(ac[ks], bf[0][ks], a0, 0, 0, 0);
      a1 = __builtin_amdgcn_mfma_f32_32x32x16_bf16(ac[ks], bf[1][ks], a1, 0, 0, 0);
    }
#pragma unroll
    for (int q = 0; q < 16; q++) {
      den0 += EXP2F(__builtin_fmaf(a0[q], 1.44269504f, -57.70780163f));
      den1 += EXP2F(__builtin_fmaf(a1[q], 1.44269504f, -57.70780163f));
    }
    if (it + 1 < 9) {
#pragma unroll
      for (int ks = 0; ks < 8; ks++) ac[ks] = an[ks];
    }
  }
  den0 += __shfl_xor(den0, 32, 64);
  den1 += __shfl_xor(den1, 32, 64);
  if (l < 32) {
    float* dp = denp + (size_t)(s * NB + b) * NN + m0 + w * 64;
    dp[lm] = den0;
    dp[32 + lm] = den1;
  }
}

// ---------------- K2b: rdn[b][m] = 1 / sum_s denp ----------------
__global__ __launch_bounds__(256) void k_rdn(const float* __restrict__ denp,
                                             float* __restrict__ rdn) {
  const int i = blockIdx.x * 256 + threadIdx.x;
  const int b = i / NN, m = i % NN;
  float s = 0.f;
#pragma unroll
  for (int s2 = 0; s2 < NSLICE; s2++) s += denp[(size_t)(s2 * NB + b) * NN + m];
  rdn[i] = 1.0f / s;
}

// ---------------- K3: fused scores+softmax+PV -> Yp slabs ----------------
// v5: Atile double-buffer (m-chunk 64), ONE barrier per chunk, PV(ch-1) || score(ch) in same region.
// grid 576: xcd=x&7, rr=x>>3, nt=rr>>1, combo c=xcd+8*(rr&1): b=c>>2, sk=c&3
__global__ __launch_bounds__(256) void k_att(const u16* __restrict__ Tt,
                                             const u16* __restrict__ Pt,
                                             const u16* __restrict__ Gn,
                                             const float* __restrict__ rdn,
                                             float* __restrict__ Yp) {
  __shared__ u16 TtS[128 * 128];      // swizzled [row][granule], 32 KB
  __shared__ u16 Atile[2][128 * 72];  // [buf][n][m64] pitch 72, 36 KB
  const int tid = threadIdx.x;
  const int w = tid >> 6, l = tid & 63, lr = l & 15, lg = l >> 4;
  const int lm = l & 31, lh = l >> 5;
  const int x = blockIdx.x;
  const int xcd = x & 7, rr = x >> 3;
  const int nt = rr >> 1;
  const int c = xcd + 8 * (rr & 1);
  const int b = c >> 2, sk = c & 3;
  const int n0 = nt * 128;
  const int mbase = sk * 1152;
  const u16* TtB = Tt + ((size_t)b * NN + n0) * CH;
  const u16* PtB = Pt + (size_t)b * NN * CH;
  const u16* GnB = Gn + (size_t)b * CH * NN;
  const float* rdnB = rdn + b * NN;

  // stage swizzled Tt tile: LDS[row][slot] = Tt[row][slot ^ (row&15)]
#pragma unroll
  for (int it = 0; it < 8; it++) {
    const int i = it * 256 + tid;
    const int row = i >> 4, slot = i & 15;
    gl_lds16(TtB + (size_t)row * CH + ((slot ^ (row & 15)) * 8),
             &TtS[(it * 256 + w * 64) * 8]);
  }

  const int wm2 = w & 1, wn2 = w >> 1;  // score roles: m-sub, n-half
  const int wc = w >> 1, wn = w & 1;    // PV roles: c-half, n-half
  f32x4 acc[4][4];
#pragma unroll
  for (int fa = 0; fa < 4; fa++)
#pragma unroll
    for (int fb = 0; fb < 4; fb++)
#pragma unroll
      for (int j = 0; j < 4; j++) acc[fa][fb][j] = 0.f;

  __syncthreads();  // TtS ready

  for (int ch = 0; ch < 19; ch++) {
    // ---- PV for chunk ch-1 (reads Atile[(ch-1)&1], written last region) ----
    if (ch >= 1) {
      const int mp = mbase + (ch - 1) * 64;
      const u16* Ab = &Atile[(ch - 1) & 1][0];
      __builtin_amdgcn_s_setprio(1);
#pragma unroll
      for (int ks = 0; ks < 2; ks++) {
        short8 gf[4], pb[4];
#pragma unroll
        for (int fa = 0; fa < 4; fa++)
          gf[fa] = *(const short8*)(GnB + (size_t)(wc * 64 + fa * 16 + lr) * NN + mp + ks * 32 + lg * 8);
#pragma unroll
        for (int fb = 0; fb < 4; fb++)
          pb[fb] = *(const short8*)(Ab + (wn * 64 + fb * 16 + lr) * 72 + ks * 32 + lg * 8);
#pragma unroll
        for (int fa = 0; fa < 4; fa++)
#pragma unroll
          for (int fb = 0; fb < 4; fb++)
            acc[fa][fb] = __builtin_amdgcn_mfma_f32_16x16x32_bf16(gf[fa], pb[fb], acc[fa][fb], 0, 0, 0);
      }
      __builtin_amdgcn_s_setprio(0);
    }
    // ---- score for chunk ch (writes Atile[ch&1]) ----
    if (ch < 18) {
      const int mch = mbase + ch * 64;
      u16* Aw = &Atile[ch & 1][0];
      short8 bf[8];
#pragma unroll
      for (int ks = 0; ks < 8; ks++)
        bf[ks] = *(const short8*)(PtB + (size_t)(mch + wm2 * 32 + lm) * CH + ks * 16 + lh * 8);
      const float rv = rdnB[mch + wm2 * 32 + lm];
#pragma unroll
      for (int ns = 0; ns < 2; ns++) {
        const int nrow = wn2 * 64 + ns * 32 + lm;
        short8 af[8];
#pragma unroll
        for (int ks = 0; ks < 8; ks++)
          af[ks] = *(const short8*)(&TtS[nrow * 128 + (((ks * 2 + lh) ^ (lm & 15)) * 8)]);
        f32x16 sa;
#pragma unroll
        for (int q = 0; q < 16; q++) sa[q] = 0.f;
#pragma unroll
        for (int ks = 0; ks < 8; ks++)
          sa = __builtin_amdgcn_mfma_f32_32x32x16_bf16(af[ks], bf[ks], sa, 0, 0, 0);
#pragma unroll
        for (int q = 0; q < 16; q += 2) {
          const int nl = wn2 * 64 + ns * 32 + (q & 3) + 8 * (q >> 2) + 4 * lh;
          float e0 = EXP2F(__builtin_fmaf(sa[q], 1.44269504f, -57.70780163f)) * rv;
          float e1 = EXP2F(__builtin_fmaf(sa[q + 1], 1.44269504f, -57.70780163f)) * rv;
          u32 pk = cvtpk(e0, e1);
          Aw[nl * 72 + wm2 * 32 + lm] = (u16)pk;
          Aw[(nl + 1) * 72 + wm2 * 32 + lm] = (u16)(pk >> 16);
        }
      }
    }
    __syncthreads();
  }
  // epilogue: write Yp slab (f32)
  float* Yb = Yp + (size_t)(sk * NB + b) * CH * NN;
#pragma unroll
  for (int fa = 0; fa < 4; fa++) {
#pragma unroll
    for (int fb = 0; fb < 4; fb++) {
      const int n = n0 + wn * 64 + fb * 16 + lr;
#pragma unroll
      for (int j = 0; j < 4; j++) {
        const int d = wc * 64 + fa * 16 + lg * 4 + j;
        Yb[(size_t)d * NN + n] = acc[fa][fb][j];
      }
    }
  }
}

// ---------------- K4: reduce Yp over 4 sk-slabs, mask-GEMM + residual ----------------
__global__ __launch_bounds__(256) void k_out(const float* __restrict__ Yp,
                                             const u16* __restrict__ wmb,
                                             const float* __restrict__ x1,
                                             float* __restrict__ out) {
  __shared__ u16 yy[64][72];
  const int tid = threadIdx.x;
  const int w = tid >> 6, l = tid & 63, lr = l & 15, lg = l >> 4;
  const int b = blockIdx.y;
  const int n0 = blockIdx.x * 32;
  const int nl = tid & 31, cch = tid >> 5;

  float v[16];
#pragma unroll
  for (int q = 0; q < 16; q++) v[q] = 0.f;
#pragma unroll
  for (int s2 = 0; s2 < 4; s2++) {
    const float* base = Yp + ((size_t)(s2 * NB + b) * CH + cch * 16) * NN + n0 + nl;
#pragma unroll
    for (int q = 0; q < 16; q++) v[q] += base[(size_t)q * NN];
  }
#pragma unroll
  for (int q = 0; q < 16; q++) {
    const int d = cch * 16 + q;  // d = h*64 + i
    yy[(d >> 6) * 32 + nl][d & 63] = f2bf(v[q]);
  }
  __syncthreads();

  const int wm3 = w >> 1, wp3 = w & 1;
  f32x4 eacc[4][2];
#pragma unroll
  for (int fa = 0; fa < 4; fa++)
#pragma unroll
    for (int fb = 0; fb < 2; fb++)
#pragma unroll
      for (int j = 0; j < 4; j++) eacc[fa][fb][j] = 0.f;
#pragma unroll
  for (int ks = 0; ks < 2; ks++) {
    short8 wa[4];
#pragma unroll
    for (int fa = 0; fa < 4; fa++)
      wa[fa] = *(const short8*)(wmb + (wm3 * 64 + fa * 16 + lr) * 64 + ks * 32 + lg * 8);
    short8 yb[2];
#pragma unroll
    for (int fb = 0; fb < 2; fb++)
      yb[fb] = *(const short8*)(&yy[wp3 * 32 + fb * 16 + lr][ks * 32 + lg * 8]);
#pragma unroll
    for (int fa = 0; fa < 4; fa++)
#pragma unroll
      for (int fb = 0; fb < 2; fb++)
        eacc[fa][fb] = __builtin_amdgcn_mfma_f32_16x16x32_bf16(wa[fa], yb[fb], eacc[fa][fb], 0, 0, 0);
  }
  const float* x1b = x1 + (size_t)b * CH * HW2;
  float* ob = out + (size_t)b * CH * HW2;
#pragma unroll
  for (int fa = 0; fa < 4; fa++) {
#pragma unroll
    for (int fb = 0; fb < 2; fb++) {
      const int pl = wp3 * 32 + fb * 16 + lr;
      const int col = n0 + (pl & 31) + (pl >> 5) * NN;
#pragma unroll
      for (int j = 0; j < 4; j++) {
        const int c = wm3 * 64 + fa * 16 + lg * 4 + j;
        const size_t o = (size_t)c * HW2 + col;
        ob[o] = eacc[fa][fb][j] + x1b[o];
      }
    }
  }
}

extern "C" void kernel_launch(void* const* d_in, const int* in_sizes, int n_in,
                              void* d_out, int out_size, void* d_ws, size_t ws_size,
                              hipStream_t stream) {
  const float* x1 = (const float*)d_in[0];
  const float* x2 = (const float*)d_in[1];
  const float* wt = (const float*)d_in[2];
  const float* wp = (const float*)d_in[3];
  const float* wg = (const float*)d_in[4];
  const float* wm = (const float*)d_in[5];
  float* out = (float*)d_out;

  char* ws = (char*)d_ws;
  const size_t SZ_T = (size_t)NB * NN * CH * 2;
  u16* Tt = (u16*)ws; ws += SZ_T;
  u16* Pt = (u16*)ws; ws += SZ_T;
  u16* Gn = (u16*)ws; ws += SZ_T;
  float* denp = (float*)ws; ws += (size_t)NSLICE * NB * NN * 4;
  float* rdn = (float*)ws; ws += (size_t)NB * NN * 4;
  u16* wtb = (u16*)ws; ws += (size_t)CH * INTER2 * 2;
  u16* wpb = (u16*)ws; ws += (size_t)CH * INTER2 * 2;
  u16* wgb = (u16*)ws; ws += (size_t)CH * INTER2 * 2;
  u16* wmb = (u16*)ws; ws += (size_t)CH * INTER2 * 2;
  float* Yp = (float*)ws; ws += (size_t)16 * CH * NN * 4;
  if (ws_size < (size_t)(ws - (char*)d_ws)) return;

  hipLaunchKernelGGL(k_wcvt, dim3(32), dim3(256), 0, stream, wt, wp, wg, wm, wtb, wpb, wgb, wmb);
  hipLaunchKernelGGL(k_conv, dim3(144, NB, 2), dim3(256), 0, stream, x1, x2, wtb, wpb, wgb, Tt, Pt, Gn);
  hipLaunchKernelGGL(k_den, dim3(288, NB), dim3(256), 0, stream, Tt, Pt, denp);
  hipLaunchKernelGGL(k_rdn, dim3(72), dim3(256), 0, stream, denp, rdn);
  hipLaunchKernelGGL(k_att, dim3(576), dim3(256), 0, stream, Tt, Pt, Gn, rdn, Yp);
  hipLaunchKernelGGL(k_out, dim3(144, NB), dim3(256), 0, stream, Yp, wmb, x1, out);
}

// Round 17
// 216.454 us; speedup vs baseline: 1.1081x; 1.0127x over previous
//
#include <hip/hip_runtime.h>

typedef __attribute__((ext_vector_type(8))) short short8;
typedef __attribute__((ext_vector_type(4))) float f32x4;
typedef __attribute__((ext_vector_type(16))) float f32x16;
typedef unsigned short u16;
typedef unsigned int u32;

#define NB 4
#define CH 128
#define INTER2 64
#define HW2 9216
#define NN 4608
#define NSLICE 16
#define SLW2 288
#define PCH 136   // xT LDS pitch (u16)
#define APITCH 136

#if __has_builtin(__builtin_amdgcn_exp2f)
#define EXP2F __builtin_amdgcn_exp2f
#else
#define EXP2F exp2f
#endif

__device__ __forceinline__ u16 f2bf(float f) {
  u32 u = __float_as_uint(f);
  u += 0x7fffu + ((u >> 16) & 1u);
  return (u16)(u >> 16);
}
__device__ __forceinline__ float bf2f(u16 h) { return __uint_as_float(((u32)h) << 16); }
__device__ __forceinline__ u32 cvtpk(float lo, float hi) {
  u32 r;
  asm("v_cvt_pk_bf16_f32 %0, %1, %2" : "=v"(r) : "v"(lo), "v"(hi));
  return r;
}
__device__ __forceinline__ void gl_lds16(const u16* g, u16* l) {
  __builtin_amdgcn_global_load_lds(
      (const __attribute__((address_space(1))) unsigned int*)g,
      (__attribute__((address_space(3))) unsigned int*)l, 16, 0, 0);
}

// ---------------- K0: all weights f32 -> bf16 ----------------
__global__ void k_wcvt(const float* __restrict__ wt, const float* __restrict__ wp,
                       const float* __restrict__ wg, const float* __restrict__ wm,
                       u16* __restrict__ wtb, u16* __restrict__ wpb,
                       u16* __restrict__ wgb, u16* __restrict__ wmb) {
  int i = blockIdx.x * 256 + threadIdx.x;
  if (i < CH * INTER2) {
    wtb[i] = f2bf(wt[i]);
    wpb[i] = f2bf(wp[i]);
    wgb[i] = f2bf(wg[i]);
    wmb[i] = f2bf(wm[i]);
  }
}

// ---------------- K1: fused conv GEMM (unchanged, proven) ----------------
__global__ __launch_bounds__(256) void k_conv(const float* __restrict__ x1,
                                              const float* __restrict__ x2,
                                              const u16* __restrict__ wtb,
                                              const u16* __restrict__ wpb,
                                              const u16* __restrict__ wgb,
                                              u16* __restrict__ Tt,
                                              u16* __restrict__ Pt,
                                              u16* __restrict__ Gn) {
  __shared__ u16 xT[64 * PCH];
  __shared__ u16 ot[64 * 72];
  const int tid = threadIdx.x;
  const int w = tid >> 6, l = tid & 63, lr = l & 15, lg = l >> 4;
  const int pt = blockIdx.x, b = blockIdx.y, z = blockIdx.z;
  const int p0 = pt * 64;
  const int h = (p0 >= NN) ? 1 : 0;
  const int n0 = p0 - h * NN;
  const float* X = (z ? x2 : x1) + (size_t)b * CH * HW2;

  {
    const int pq = (l & 15) * 4;
    const int cs = w + 4 * (l >> 4);
#pragma unroll
    for (int it = 0; it < 8; it++) {
      const int c = it * 16 + cs;
      float4 v = *(const float4*)(X + (size_t)c * HW2 + p0 + pq);
      xT[(pq + 0) * PCH + c] = f2bf(v.x);
      xT[(pq + 1) * PCH + c] = f2bf(v.y);
      xT[(pq + 2) * PCH + c] = f2bf(v.z);
      xT[(pq + 3) * PCH + c] = f2bf(v.w);
    }
  }
  short8 wsP[4], wsG[4];
  {
    const u16* W1 = z ? wpb : wtb;
#pragma unroll
    for (int ks = 0; ks < 4; ks++)
      wsP[ks] = *(const short8*)(W1 + (w * 16 + lr) * CH + ks * 32 + lg * 8);
    if (z) {
#pragma unroll
      for (int ks = 0; ks < 4; ks++)
        wsG[ks] = *(const short8*)(wgb + (w * 16 + lr) * CH + ks * 32 + lg * 8);
    }
  }
  __syncthreads();
  short8 xf[4][4];
#pragma unroll
  for (int tp = 0; tp < 4; tp++)
#pragma unroll
    for (int ks = 0; ks < 4; ks++)
      xf[tp][ks] = *(const short8*)(&xT[(tp * 16 + lr) * PCH + ks * 32 + lg * 8]);

  f32x4 accP[4];
#pragma unroll
  for (int tp = 0; tp < 4; tp++) {
#pragma unroll
    for (int j = 0; j < 4; j++) accP[tp][j] = 0.f;
#pragma unroll
    for (int ks = 0; ks < 4; ks++)
      accP[tp] = __builtin_amdgcn_mfma_f32_16x16x32_bf16(xf[tp][ks], wsP[ks], accP[tp], 0, 0, 0);
  }
#pragma unroll
  for (int tp = 0; tp < 4; tp++) {
#pragma unroll
    for (int j = 0; j < 4; j++)
      ot[(tp * 16 + lg * 4 + j) * 72 + w * 16 + lr] = f2bf(accP[tp][j]);
  }
  if (z) {
    f32x4 accG[4];
#pragma unroll
    for (int tp = 0; tp < 4; tp++) {
#pragma unroll
      for (int j = 0; j < 4; j++) accG[tp][j] = 0.f;
#pragma unroll
      for (int ks = 0; ks < 4; ks++)
        accG[tp] = __builtin_amdgcn_mfma_f32_16x16x32_bf16(wsG[ks], xf[tp][ks], accG[tp], 0, 0, 0);
    }
    u16* Gb = Gn + (size_t)b * CH * NN;
#pragma unroll
    for (int tp = 0; tp < 4; tp++) {
#pragma unroll
      for (int j = 0; j < 4; j++) {
        const int ig = w * 16 + lg * 4 + j;
        Gb[(size_t)((h << 6) + ig) * NN + n0 + tp * 16 + lr] = f2bf(accG[tp][j]);
      }
    }
  }
  __syncthreads();
  {
    u16* dst = (z ? Pt : Tt) + (size_t)b * NN * CH;
#pragma unroll
    for (int q = 0; q < 2; q++) {
      const int idx = tid * 2 + q;
      const int p = idx >> 3, c8 = (idx & 7) * 8;
      uint4 v = *(const uint4*)(&ot[p * 72 + c8]);
      *(uint4*)(dst + (size_t)(n0 + p) * CH + h * 64 + c8) = v;
    }
  }
}

// ---------------- K2: den-only pass. m-tile 256 resident, 16 n-slices ----------------
__global__ __launch_bounds__(256) void k_den(const u16* __restrict__ Tt,
                                             const u16* __restrict__ Pt,
                                             float* __restrict__ denp) {
  const int tid = threadIdx.x;
  const int w = tid >> 6, l = tid & 63, lm = l & 31, lh = l >> 5;
  const int s = blockIdx.x & 15, mt = blockIdx.x >> 4;
  const int b = blockIdx.y;
  const int m0 = mt * 256;
  const int nbase = s * SLW2;
  const u16* PtB = Pt + (size_t)b * NN * CH;
  const u16* TtB = Tt + (size_t)b * NN * CH;

  short8 bf[2][8];
#pragma unroll
  for (int ms = 0; ms < 2; ms++)
#pragma unroll
    for (int ks = 0; ks < 8; ks++)
      bf[ms][ks] = *(const short8*)(PtB + (size_t)(m0 + w * 64 + ms * 32 + lm) * CH + ks * 16 + lh * 8);

  float den0 = 0.f, den1 = 0.f;
  short8 ac[8], an[8];
#pragma unroll
  for (int ks = 0; ks < 8; ks++)
    ac[ks] = *(const short8*)(TtB + (size_t)(nbase + lm) * CH + ks * 16 + lh * 8);

  for (int it = 0; it < 9; it++) {
    if (it + 1 < 9) {
      const int nr = nbase + (it + 1) * 32 + lm;
#pragma unroll
      for (int ks = 0; ks < 8; ks++)
        an[ks] = *(const short8*)(TtB + (size_t)nr * CH + ks * 16 + lh * 8);
    }
    f32x16 a0, a1;
#pragma unroll
    for (int q = 0; q < 16; q++) { a0[q] = 0.f; a1[q] = 0.f; }
#pragma unroll
    for (int ks = 0; ks < 8; ks++) {
      a0 = __builtin_amdgcn_mfma_f32_32x32x16_bf16(ac[ks], bf[0][ks], a0, 0, 0, 0);
      a1 = __builtin_amdgcn_mfma_f32_32x32x16_bf16(ac[ks], bf[1][ks], a1, 0, 0, 0);
    }
#pragma unroll
    for (int q = 0; q < 16; q++) {
      den0 += EXP2F(__builtin_fmaf(a0[q], 1.44269504f, -57.70780163f));
      den1 += EXP2F(__builtin_fmaf(a1[q], 1.44269504f, -57.70780163f));
    }
    if (it + 1 < 9) {
#pragma unroll
      for (int ks = 0; ks < 8; ks++) ac[ks] = an[ks];
    }
  }
  den0 += __shfl_xor(den0, 32, 64);
  den1 += __shfl_xor(den1, 32, 64);
  if (l < 32) {
    float* dp = denp + (size_t)(s * NB + b) * NN + m0 + w * 64;
    dp[lm] = den0;
    dp[32 + lm] = den1;
  }
}

// ---------------- K2b: rdn[b][m] = 1 / sum_s denp ----------------
__global__ __launch_bounds__(256) void k_rdn(const float* __restrict__ denp,
                                             float* __restrict__ rdn) {
  const int i = blockIdx.x * 256 + threadIdx.x;
  const int b = i / NN, m = i % NN;
  float s = 0.f;
#pragma unroll
  for (int s2 = 0; s2 < NSLICE; s2++) s += denp[(size_t)(s2 * NB + b) * NN + m];
  rdn[i] = 1.0f / s;
}

// ---------------- K3: fused scores+softmax+PV -> Yp slabs (R12 structure, n-tile 64 -> 4 blocks/CU) ----------------
// grid 1152: xcd=x&7, rr=x>>3 (0..143), nt=rr>>1 (0..71), c=xcd+8*(rr&1): b=c>>2, sk=c&3
__global__ __launch_bounds__(256) void k_att(const u16* __restrict__ Tt,
                                             const u16* __restrict__ Pt,
                                             const u16* __restrict__ Gn,
                                             const float* __restrict__ rdn,
                                             float* __restrict__ Yp) {
  __shared__ u16 TtS[64 * 128];       // swizzled [row][granule], 16 KB
  __shared__ u16 Atile[64 * APITCH];  // [n][m] pitch 136, 17.4 KB
  const int tid = threadIdx.x;
  const int w = tid >> 6, l = tid & 63, lr = l & 15, lg = l >> 4;
  const int lm = l & 31, lh = l >> 5;
  const int x = blockIdx.x;
  const int xcd = x & 7, rr = x >> 3;
  const int nt = rr >> 1;
  const int c = xcd + 8 * (rr & 1);
  const int b = c >> 2, sk = c & 3;
  const int n0 = nt * 64;
  const int mbase = sk * 1152;
  const u16* TtB = Tt + ((size_t)b * NN + n0) * CH;
  const u16* PtB = Pt + (size_t)b * NN * CH;
  const u16* GnB = Gn + (size_t)b * CH * NN;
  const float* rdnB = rdn + b * NN;

  // stage swizzled Tt tile (64 rows): LDS[row][slot] = Tt[row][slot ^ (row&15)]
#pragma unroll
  for (int it = 0; it < 4; it++) {
    const int i = it * 256 + tid;
    const int row = i >> 4, slot = i & 15;
    gl_lds16(TtB + (size_t)row * CH + ((slot ^ (row & 15)) * 8),
             &TtS[(it * 256 + w * 64) * 8]);
  }
  __syncthreads();

  const int wc = w >> 1, wn = w & 1;
  f32x4 acc[4][2];
#pragma unroll
  for (int fa = 0; fa < 4; fa++)
#pragma unroll
    for (int fb = 0; fb < 2; fb++)
#pragma unroll
      for (int j = 0; j < 4; j++) acc[fa][fb][j] = 0.f;

  for (int ch = 0; ch < 9; ch++) {
    const int mch = mbase + ch * 128;
    // ---- score phase: wave w owns m-sub w (32 m), all 64 n ----
    short8 bf[8];
#pragma unroll
    for (int ks = 0; ks < 8; ks++)
      bf[ks] = *(const short8*)(PtB + (size_t)(mch + w * 32 + lm) * CH + ks * 16 + lh * 8);
    const float rv = rdnB[mch + w * 32 + lm];
#pragma unroll
    for (int ns = 0; ns < 2; ns++) {
      const int nrow = ns * 32 + lm;
      short8 af[8];
#pragma unroll
      for (int ks = 0; ks < 8; ks++)
        af[ks] = *(const short8*)(&TtS[nrow * 128 + (((ks * 2 + lh) ^ (lm & 15)) * 8)]);
      f32x16 sa;
#pragma unroll
      for (int q = 0; q < 16; q++) sa[q] = 0.f;
#pragma unroll
      for (int ks = 0; ks < 8; ks++)
        sa = __builtin_amdgcn_mfma_f32_32x32x16_bf16(af[ks], bf[ks], sa, 0, 0, 0);
#pragma unroll
      for (int q = 0; q < 16; q += 2) {
        const int nl = ns * 32 + (q & 3) + 8 * (q >> 2) + 4 * lh;
        float e0 = EXP2F(__builtin_fmaf(sa[q], 1.44269504f, -57.70780163f)) * rv;
        float e1 = EXP2F(__builtin_fmaf(sa[q + 1], 1.44269504f, -57.70780163f)) * rv;
        u32 pk = cvtpk(e0, e1);
        Atile[nl * APITCH + w * 32 + lm] = (u16)pk;
        Atile[(nl + 1) * APITCH + w * 32 + lm] = (u16)(pk >> 16);
      }
    }
    // issue PV ks=0 gf loads before the barrier (latency hides under barrier wait)
    short8 gfc[4], gfn2[4];
#pragma unroll
    for (int fa = 0; fa < 4; fa++)
      gfc[fa] = *(const short8*)(GnB + (size_t)(wc * 64 + fa * 16 + lr) * NN + mch + lg * 8);
    __syncthreads();
    // ---- PV phase: wave (wc,wn): c-half 64, n-half 32; K = 128 m; gf one-ks-ahead ----
#pragma unroll
    for (int ks = 0; ks < 4; ks++) {
      if (ks + 1 < 4) {
#pragma unroll
        for (int fa = 0; fa < 4; fa++)
          gfn2[fa] = *(const short8*)(GnB + (size_t)(wc * 64 + fa * 16 + lr) * NN + mch + (ks + 1) * 32 + lg * 8);
      }
      short8 pb[2];
#pragma unroll
      for (int fb = 0; fb < 2; fb++)
        pb[fb] = *(const short8*)(&Atile[(wn * 32 + fb * 16 + lr) * APITCH + ks * 32 + lg * 8]);
#pragma unroll
      for (int fa = 0; fa < 4; fa++)
#pragma unroll
        for (int fb = 0; fb < 2; fb++)
          acc[fa][fb] = __builtin_amdgcn_mfma_f32_16x16x32_bf16(gfc[fa], pb[fb], acc[fa][fb], 0, 0, 0);
      if (ks + 1 < 4) {
#pragma unroll
        for (int fa = 0; fa < 4; fa++) gfc[fa] = gfn2[fa];
      }
    }
    __syncthreads();
  }
  // epilogue: write Yp slab (f32)
  float* Yb = Yp + (size_t)(sk * NB + b) * CH * NN;
#pragma unroll
  for (int fa = 0; fa < 4; fa++) {
#pragma unroll
    for (int fb = 0; fb < 2; fb++) {
      const int n = n0 + wn * 32 + fb * 16 + lr;
#pragma unroll
      for (int j = 0; j < 4; j++) {
        const int d = wc * 64 + fa * 16 + lg * 4 + j;
        Yb[(size_t)d * NN + n] = acc[fa][fb][j];
      }
    }
  }
}

// ---------------- K4: reduce Yp over 4 sk-slabs, mask-GEMM + residual ----------------
__global__ __launch_bounds__(256) void k_out(const float* __restrict__ Yp,
                                             const u16* __restrict__ wmb,
                                             const float* __restrict__ x1,
                                             float* __restrict__ out) {
  __shared__ u16 yy[64][72];
  const int tid = threadIdx.x;
  const int w = tid >> 6, l = tid & 63, lr = l & 15, lg = l >> 4;
  const int b = blockIdx.y;
  const int n0 = blockIdx.x * 32;
  const int nl = tid & 31, cch = tid >> 5;

  float v[16];
#pragma unroll
  for (int q = 0; q < 16; q++) v[q] = 0.f;
#pragma unroll
  for (int s2 = 0; s2 < 4; s2++) {
    const float* base = Yp + ((size_t)(s2 * NB + b) * CH + cch * 16) * NN + n0 + nl;
#pragma unroll
    for (int q = 0; q < 16; q++) v[q] += base[(size_t)q * NN];
  }
#pragma unroll
  for (int q = 0; q < 16; q++) {
    const int d = cch * 16 + q;  // d = h*64 + i
    yy[(d >> 6) * 32 + nl][d & 63] = f2bf(v[q]);
  }
  __syncthreads();

  const int wm3 = w >> 1, wp3 = w & 1;
  f32x4 eacc[4][2];
#pragma unroll
  for (int fa = 0; fa < 4; fa++)
#pragma unroll
    for (int fb = 0; fb < 2; fb++)
#pragma unroll
      for (int j = 0; j < 4; j++) eacc[fa][fb][j] = 0.f;
#pragma unroll
  for (int ks = 0; ks < 2; ks++) {
    short8 wa[4];
#pragma unroll
    for (int fa = 0; fa < 4; fa++)
      wa[fa] = *(const short8*)(wmb + (wm3 * 64 + fa * 16 + lr) * 64 + ks * 32 + lg * 8);
    short8 yb[2];
#pragma unroll
    for (int fb = 0; fb < 2; fb++)
      yb[fb] = *(const short8*)(&yy[wp3 * 32 + fb * 16 + lr][ks * 32 + lg * 8]);
#pragma unroll
    for (int fa = 0; fa < 4; fa++)
#pragma unroll
      for (int fb = 0; fb < 2; fb++)
        eacc[fa][fb] = __builtin_amdgcn_mfma_f32_16x16x32_bf16(wa[fa], yb[fb], eacc[fa][fb], 0, 0, 0);
  }
  const float* x1b = x1 + (size_t)b * CH * HW2;
  float* ob = out + (size_t)b * CH * HW2;
#pragma unroll
  for (int fa = 0; fa < 4; fa++) {
#pragma unroll
    for (int fb = 0; fb < 2; fb++) {
      const int pl = wp3 * 32 + fb * 16 + lr;
      const int col = n0 + (pl & 31) + (pl >> 5) * NN;
#pragma unroll
      for (int j = 0; j < 4; j++) {
        const int c = wm3 * 64 + fa * 16 + lg * 4 + j;
        const size_t o = (size_t)c * HW2 + col;
        ob[o] = eacc[fa][fb][j] + x1b[o];
      }
    }
  }
}

extern "C" void kernel_launch(void* const* d_in, const int* in_sizes, int n_in,
                              void* d_out, int out_size, void* d_ws, size_t ws_size,
                              hipStream_t stream) {
  const float* x1 = (const float*)d_in[0];
  const float* x2 = (const float*)d_in[1];
  const float* wt = (const float*)d_in[2];
  const float* wp = (const float*)d_in[3];
  const float* wg = (const float*)d_in[4];
  const float* wm = (const float*)d_in[5];
  float* out = (float*)d_out;

  char* ws = (char*)d_ws;
  const size_t SZ_T = (size_t)NB * NN * CH * 2;
  u16* Tt = (u16*)ws; ws += SZ_T;
  u16* Pt = (u16*)ws; ws += SZ_T;
  u16* Gn = (u16*)ws; ws += SZ_T;
  float* denp = (float*)ws; ws += (size_t)NSLICE * NB * NN * 4;
  float* rdn = (float*)ws; ws += (size_t)NB * NN * 4;
  u16* wtb = (u16*)ws; ws += (size_t)CH * INTER2 * 2;
  u16* wpb = (u16*)ws; ws += (size_t)CH * INTER2 * 2;
  u16* wgb = (u16*)ws; ws += (size_t)CH * INTER2 * 2;
  u16* wmb = (u16*)ws; ws += (size_t)CH * INTER2 * 2;
  float* Yp = (float*)ws; ws += (size_t)16 * CH * NN * 4;
  if (ws_size < (size_t)(ws - (char*)d_ws)) return;

  hipLaunchKernelGGL(k_wcvt, dim3(32), dim3(256), 0, stream, wt, wp, wg, wm, wtb, wpb, wgb, wmb);
  hipLaunchKernelGGL(k_conv, dim3(144, NB, 2), dim3(256), 0, stream, x1, x2, wtb, wpb, wgb, Tt, Pt, Gn);
  hipLaunchKernelGGL(k_den, dim3(288, NB), dim3(256), 0, stream, Tt, Pt, denp);
  hipLaunchKernelGGL(k_rdn, dim3(72), dim3(256), 0, stream, denp, rdn);
  hipLaunchKernelGGL(k_att, dim3(1152), dim3(256), 0, stream, Tt, Pt, Gn, rdn, Yp);
  hipLaunchKernelGGL(k_out, dim3(144, NB), dim3(256), 0, stream, Yp, wmb, x1, out);
}

// Round 18
// 168.897 us; speedup vs baseline: 1.4201x; 1.2816x over previous
//
#include <hip/hip_runtime.h>

typedef __attribute__((ext_vector_type(8))) short short8;
typedef __attribute__((ext_vector_type(4))) float f32x4;
typedef __attribute__((ext_vector_type(16))) float f32x16;
typedef unsigned short u16;
typedef unsigned int u32;

#define NB 4
#define CH 128
#define INTER2 64
#define HW2 9216
#define NN 4608
#define NSLICE 16
#define SLW2 288
#define PCH 136   // xT LDS pitch (u16)
#define APITCH 136
#define NSK 6     // m-splits for k_att (768 m each, 6 chunks of 128)

#if __has_builtin(__builtin_amdgcn_exp2f)
#define EXP2F __builtin_amdgcn_exp2f
#else
#define EXP2F exp2f
#endif

__device__ __forceinline__ u16 f2bf(float f) {
  u32 u = __float_as_uint(f);
  u += 0x7fffu + ((u >> 16) & 1u);
  return (u16)(u >> 16);
}
__device__ __forceinline__ float bf2f(u16 h) { return __uint_as_float(((u32)h) << 16); }
__device__ __forceinline__ u32 cvtpk(float lo, float hi) {
  u32 r;
  asm("v_cvt_pk_bf16_f32 %0, %1, %2" : "=v"(r) : "v"(lo), "v"(hi));
  return r;
}
__device__ __forceinline__ void gl_lds16(const u16* g, u16* l) {
  __builtin_amdgcn_global_load_lds(
      (const __attribute__((address_space(1))) unsigned int*)g,
      (__attribute__((address_space(3))) unsigned int*)l, 16, 0, 0);
}

// ---------------- K0: all weights f32 -> bf16 ----------------
__global__ void k_wcvt(const float* __restrict__ wt, const float* __restrict__ wp,
                       const float* __restrict__ wg, const float* __restrict__ wm,
                       u16* __restrict__ wtb, u16* __restrict__ wpb,
                       u16* __restrict__ wgb, u16* __restrict__ wmb) {
  int i = blockIdx.x * 256 + threadIdx.x;
  if (i < CH * INTER2) {
    wtb[i] = f2bf(wt[i]);
    wpb[i] = f2bf(wp[i]);
    wgb[i] = f2bf(wg[i]);
    wmb[i] = f2bf(wm[i]);
  }
}

// ---------------- K1: fused conv GEMM (R12 + batched staging loads) ----------------
__global__ __launch_bounds__(256) void k_conv(const float* __restrict__ x1,
                                              const float* __restrict__ x2,
                                              const u16* __restrict__ wtb,
                                              const u16* __restrict__ wpb,
                                              const u16* __restrict__ wgb,
                                              u16* __restrict__ Tt,
                                              u16* __restrict__ Pt,
                                              u16* __restrict__ Gn) {
  __shared__ u16 xT[64 * PCH];
  __shared__ u16 ot[64 * 72];
  const int tid = threadIdx.x;
  const int w = tid >> 6, l = tid & 63, lr = l & 15, lg = l >> 4;
  const int pt = blockIdx.x, b = blockIdx.y, z = blockIdx.z;
  const int p0 = pt * 64;
  const int h = (p0 >= NN) ? 1 : 0;
  const int n0 = p0 - h * NN;
  const float* X = (z ? x2 : x1) + (size_t)b * CH * HW2;

  {
    const int pq = (l & 15) * 4;
    const int cs = w + 4 * (l >> 4);
    float4 va[8];
#pragma unroll
    for (int it = 0; it < 8; it++) {
      const int c = it * 16 + cs;
      va[it] = *(const float4*)(X + (size_t)c * HW2 + p0 + pq);
    }
#pragma unroll
    for (int it = 0; it < 8; it++) {
      const int c = it * 16 + cs;
      xT[(pq + 0) * PCH + c] = f2bf(va[it].x);
      xT[(pq + 1) * PCH + c] = f2bf(va[it].y);
      xT[(pq + 2) * PCH + c] = f2bf(va[it].z);
      xT[(pq + 3) * PCH + c] = f2bf(va[it].w);
    }
  }
  short8 wsP[4], wsG[4];
  {
    const u16* W1 = z ? wpb : wtb;
#pragma unroll
    for (int ks = 0; ks < 4; ks++)
      wsP[ks] = *(const short8*)(W1 + (w * 16 + lr) * CH + ks * 32 + lg * 8);
    if (z) {
#pragma unroll
      for (int ks = 0; ks < 4; ks++)
        wsG[ks] = *(const short8*)(wgb + (w * 16 + lr) * CH + ks * 32 + lg * 8);
    }
  }
  __syncthreads();
  short8 xf[4][4];
#pragma unroll
  for (int tp = 0; tp < 4; tp++)
#pragma unroll
    for (int ks = 0; ks < 4; ks++)
      xf[tp][ks] = *(const short8*)(&xT[(tp * 16 + lr) * PCH + ks * 32 + lg * 8]);

  f32x4 accP[4];
#pragma unroll
  for (int tp = 0; tp < 4; tp++) {
#pragma unroll
    for (int j = 0; j < 4; j++) accP[tp][j] = 0.f;
#pragma unroll
    for (int ks = 0; ks < 4; ks++)
      accP[tp] = __builtin_amdgcn_mfma_f32_16x16x32_bf16(xf[tp][ks], wsP[ks], accP[tp], 0, 0, 0);
  }
#pragma unroll
  for (int tp = 0; tp < 4; tp++) {
#pragma unroll
    for (int j = 0; j < 4; j++)
      ot[(tp * 16 + lg * 4 + j) * 72 + w * 16 + lr] = f2bf(accP[tp][j]);
  }
  if (z) {
    f32x4 accG[4];
#pragma unroll
    for (int tp = 0; tp < 4; tp++) {
#pragma unroll
      for (int j = 0; j < 4; j++) accG[tp][j] = 0.f;
#pragma unroll
      for (int ks = 0; ks < 4; ks++)
        accG[tp] = __builtin_amdgcn_mfma_f32_16x16x32_bf16(wsG[ks], xf[tp][ks], accG[tp], 0, 0, 0);
    }
    u16* Gb = Gn + (size_t)b * CH * NN;
#pragma unroll
    for (int tp = 0; tp < 4; tp++) {
#pragma unroll
      for (int j = 0; j < 4; j++) {
        const int ig = w * 16 + lg * 4 + j;
        Gb[(size_t)((h << 6) + ig) * NN + n0 + tp * 16 + lr] = f2bf(accG[tp][j]);
      }
    }
  }
  __syncthreads();
  {
    u16* dst = (z ? Pt : Tt) + (size_t)b * NN * CH;
#pragma unroll
    for (int q = 0; q < 2; q++) {
      const int idx = tid * 2 + q;
      const int p = idx >> 3, c8 = (idx & 7) * 8;
      uint4 v = *(const uint4*)(&ot[p * 72 + c8]);
      *(uint4*)(dst + (size_t)(n0 + p) * CH + h * 64 + c8) = v;
    }
  }
}

// ---------------- K2: den-only pass. m-tile 256 resident, 16 n-slices ----------------
__global__ __launch_bounds__(256) void k_den(const u16* __restrict__ Tt,
                                             const u16* __restrict__ Pt,
                                             float* __restrict__ denp) {
  const int tid = threadIdx.x;
  const int w = tid >> 6, l = tid & 63, lm = l & 31, lh = l >> 5;
  const int s = blockIdx.x & 15, mt = blockIdx.x >> 4;
  const int b = blockIdx.y;
  const int m0 = mt * 256;
  const int nbase = s * SLW2;
  const u16* PtB = Pt + (size_t)b * NN * CH;
  const u16* TtB = Tt + (size_t)b * NN * CH;

  short8 bf[2][8];
#pragma unroll
  for (int ms = 0; ms < 2; ms++)
#pragma unroll
    for (int ks = 0; ks < 8; ks++)
      bf[ms][ks] = *(const short8*)(PtB + (size_t)(m0 + w * 64 + ms * 32 + lm) * CH + ks * 16 + lh * 8);

  float den0 = 0.f, den1 = 0.f;
  short8 ac[8], an[8];
#pragma unroll
  for (int ks = 0; ks < 8; ks++)
    ac[ks] = *(const short8*)(TtB + (size_t)(nbase + lm) * CH + ks * 16 + lh * 8);

  for (int it = 0; it < 9; it++) {
    if (it + 1 < 9) {
      const int nr = nbase + (it + 1) * 32 + lm;
#pragma unroll
      for (int ks = 0; ks < 8; ks++)
        an[ks] = *(const short8*)(TtB + (size_t)nr * CH + ks * 16 + lh * 8);
    }
    f32x16 a0, a1;
#pragma unroll
    for (int q = 0; q < 16; q++) { a0[q] = 0.f; a1[q] = 0.f; }
#pragma unroll
    for (int ks = 0; ks < 8; ks++) {
      a0 = __builtin_amdgcn_mfma_f32_32x32x16_bf16(ac[ks], bf[0][ks], a0, 0, 0, 0);
      a1 = __builtin_amdgcn_mfma_f32_32x32x16_bf16(ac[ks], bf[1][ks], a1, 0, 0, 0);
    }
#pragma unroll
    for (int q = 0; q < 16; q++) {
      den0 += EXP2F(__builtin_fmaf(a0[q], 1.44269504f, -57.70780163f));
      den1 += EXP2F(__builtin_fmaf(a1[q], 1.44269504f, -57.70780163f));
    }
    if (it + 1 < 9) {
#pragma unroll
      for (int ks = 0; ks < 8; ks++) ac[ks] = an[ks];
    }
  }
  den0 += __shfl_xor(den0, 32, 64);
  den1 += __shfl_xor(den1, 32, 64);
  if (l < 32) {
    float* dp = denp + (size_t)(s * NB + b) * NN + m0 + w * 64;
    dp[lm] = den0;
    dp[32 + lm] = den1;
  }
}

// ---------------- K2b: rdn[b][m] = 1 / sum_s denp ----------------
__global__ __launch_bounds__(256) void k_rdn(const float* __restrict__ denp,
                                             float* __restrict__ rdn) {
  const int i = blockIdx.x * 256 + threadIdx.x;
  const int b = i / NN, m = i % NN;
  float s = 0.f;
#pragma unroll
  for (int s2 = 0; s2 < NSLICE; s2++) s += denp[(size_t)(s2 * NB + b) * NN + m];
  rdn[i] = 1.0f / s;
}

// ---------------- K3: fused scores+softmax+PV -> Yp slabs (R12 structure, sk=6 for tail balance) ----------------
// grid 864: xcd=x&7; j=x>>3 (0..107); c = xcd + 8*(j%3) in [0,24); nt = j/3; b=c&3 (fixed per XCD), sk=c>>2
__global__ __launch_bounds__(256) void k_att(const u16* __restrict__ Tt,
                                             const u16* __restrict__ Pt,
                                             const u16* __restrict__ Gn,
                                             const float* __restrict__ rdn,
                                             float* __restrict__ Yp) {
  __shared__ u16 TtS[128 * 128];       // swizzled [row][granule], 32 KB
  __shared__ u16 Atile[128 * APITCH];  // [n][m] pitch 136, 34 KB
  const int tid = threadIdx.x;
  const int w = tid >> 6, l = tid & 63, lr = l & 15, lg = l >> 4;
  const int lm = l & 31, lh = l >> 5;
  const int x = blockIdx.x;
  const int xcd = x & 7, j = x >> 3;
  const int c = xcd + 8 * (j % 3);
  const int nt = j / 3;
  const int b = c & 3, sk = c >> 2;
  const int n0 = nt * 128;
  const int mbase = sk * 768;
  const u16* TtB = Tt + ((size_t)b * NN + n0) * CH;
  const u16* PtB = Pt + (size_t)b * NN * CH;
  const u16* GnB = Gn + (size_t)b * CH * NN;
  const float* rdnB = rdn + b * NN;

  // stage swizzled Tt tile: LDS[row][slot] = Tt[row][slot ^ (row&15)]
#pragma unroll
  for (int it = 0; it < 8; it++) {
    const int i = it * 256 + tid;
    const int row = i >> 4, slot = i & 15;
    gl_lds16(TtB + (size_t)row * CH + ((slot ^ (row & 15)) * 8),
             &TtS[(it * 256 + w * 64) * 8]);
  }
  __syncthreads();

  const int wc = w >> 1, wn = w & 1;
  f32x4 acc[4][4];
#pragma unroll
  for (int fa = 0; fa < 4; fa++)
#pragma unroll
    for (int fb = 0; fb < 4; fb++)
#pragma unroll
      for (int j2 = 0; j2 < 4; j2++) acc[fa][fb][j2] = 0.f;

  for (int ch = 0; ch < 6; ch++) {
    const int mch = mbase + ch * 128;
    // ---- score phase: wave w owns m-sub w (32 m), all 128 n ----
    short8 bf[8];
#pragma unroll
    for (int ks = 0; ks < 8; ks++)
      bf[ks] = *(const short8*)(PtB + (size_t)(mch + w * 32 + lm) * CH + ks * 16 + lh * 8);
    const float rv = rdnB[mch + w * 32 + lm];
#pragma unroll
    for (int ns = 0; ns < 4; ns++) {
      short8 af[8];
#pragma unroll
      for (int ks = 0; ks < 8; ks++)
        af[ks] = *(const short8*)(&TtS[(ns * 32 + lm) * 128 + (((ks * 2 + lh) ^ (lm & 15)) * 8)]);
      f32x16 sa;
#pragma unroll
      for (int q = 0; q < 16; q++) sa[q] = 0.f;
#pragma unroll
      for (int ks = 0; ks < 8; ks++)
        sa = __builtin_amdgcn_mfma_f32_32x32x16_bf16(af[ks], bf[ks], sa, 0, 0, 0);
#pragma unroll
      for (int q = 0; q < 16; q += 2) {
        const int nl = ns * 32 + (q & 3) + 8 * (q >> 2) + 4 * lh;
        float e0 = EXP2F(__builtin_fmaf(sa[q], 1.44269504f, -57.70780163f)) * rv;
        float e1 = EXP2F(__builtin_fmaf(sa[q + 1], 1.44269504f, -57.70780163f)) * rv;
        u32 pk = cvtpk(e0, e1);
        Atile[nl * APITCH + w * 32 + lm] = (u16)pk;
        Atile[(nl + 1) * APITCH + w * 32 + lm] = (u16)(pk >> 16);
      }
    }
    // issue PV ks=0 gf loads before the barrier (latency hides under barrier wait)
    short8 gfc[4], gfn2[4];
#pragma unroll
    for (int fa = 0; fa < 4; fa++)
      gfc[fa] = *(const short8*)(GnB + (size_t)(wc * 64 + fa * 16 + lr) * NN + mch + lg * 8);
    __syncthreads();
    // ---- PV phase: wave (wc,wn): c-half, n-half; K = 128 m; gf one-ks-ahead ----
#pragma unroll
    for (int ks = 0; ks < 4; ks++) {
      if (ks + 1 < 4) {
#pragma unroll
        for (int fa = 0; fa < 4; fa++)
          gfn2[fa] = *(const short8*)(GnB + (size_t)(wc * 64 + fa * 16 + lr) * NN + mch + (ks + 1) * 32 + lg * 8);
      }
      short8 pb[4];
#pragma unroll
      for (int fb = 0; fb < 4; fb++)
        pb[fb] = *(const short8*)(&Atile[(wn * 64 + fb * 16 + lr) * APITCH + ks * 32 + lg * 8]);
#pragma unroll
      for (int fa = 0; fa < 4; fa++)
#pragma unroll
        for (int fb = 0; fb < 4; fb++)
          acc[fa][fb] = __builtin_amdgcn_mfma_f32_16x16x32_bf16(gfc[fa], pb[fb], acc[fa][fb], 0, 0, 0);
      if (ks + 1 < 4) {
#pragma unroll
        for (int fa = 0; fa < 4; fa++) gfc[fa] = gfn2[fa];
      }
    }
    __syncthreads();
  }
  // epilogue: write Yp slab (f32)
  float* Yb = Yp + (size_t)(sk * NB + b) * CH * NN;
#pragma unroll
  for (int fa = 0; fa < 4; fa++) {
#pragma unroll
    for (int fb = 0; fb < 4; fb++) {
      const int n = n0 + wn * 64 + fb * 16 + lr;
#pragma unroll
      for (int j2 = 0; j2 < 4; j2++) {
        const int d = wc * 64 + fa * 16 + lg * 4 + j2;
        Yb[(size_t)d * NN + n] = acc[fa][fb][j2];
      }
    }
  }
}

// ---------------- K4: reduce Yp over NSK sk-slabs, mask-GEMM + residual ----------------
__global__ __launch_bounds__(256) void k_out(const float* __restrict__ Yp,
                                             const u16* __restrict__ wmb,
                                             const float* __restrict__ x1,
                                             float* __restrict__ out) {
  __shared__ u16 yy[64][72];
  const int tid = threadIdx.x;
  const int w = tid >> 6, l = tid & 63, lr = l & 15, lg = l >> 4;
  const int b = blockIdx.y;
  const int n0 = blockIdx.x * 32;
  const int nl = tid & 31, cch = tid >> 5;

  float v[16];
#pragma unroll
  for (int q = 0; q < 16; q++) v[q] = 0.f;
#pragma unroll
  for (int s2 = 0; s2 < NSK; s2++) {
    const float* base = Yp + ((size_t)(s2 * NB + b) * CH + cch * 16) * NN + n0 + nl;
#pragma unroll
    for (int q = 0; q < 16; q++) v[q] += base[(size_t)q * NN];
  }
#pragma unroll
  for (int q = 0; q < 16; q++) {
    const int d = cch * 16 + q;  // d = h*64 + i
    yy[(d >> 6) * 32 + nl][d & 63] = f2bf(v[q]);
  }
  __syncthreads();

  const int wm3 = w >> 1, wp3 = w & 1;
  f32x4 eacc[4][2];
#pragma unroll
  for (int fa = 0; fa < 4; fa++)
#pragma unroll
    for (int fb = 0; fb < 2; fb++)
#pragma unroll
      for (int j = 0; j < 4; j++) eacc[fa][fb][j] = 0.f;
#pragma unroll
  for (int ks = 0; ks < 2; ks++) {
    short8 wa[4];
#pragma unroll
    for (int fa = 0; fa < 4; fa++)
      wa[fa] = *(const short8*)(wmb + (wm3 * 64 + fa * 16 + lr) * 64 + ks * 32 + lg * 8);
    short8 yb[2];
#pragma unroll
    for (int fb = 0; fb < 2; fb++)
      yb[fb] = *(const short8*)(&yy[wp3 * 32 + fb * 16 + lr][ks * 32 + lg * 8]);
#pragma unroll
    for (int fa = 0; fa < 4; fa++)
#pragma unroll
      for (int fb = 0; fb < 2; fb++)
        eacc[fa][fb] = __builtin_amdgcn_mfma_f32_16x16x32_bf16(wa[fa], yb[fb], eacc[fa][fb], 0, 0, 0);
  }
  const float* x1b = x1 + (size_t)b * CH * HW2;
  float* ob = out + (size_t)b * CH * HW2;
#pragma unroll
  for (int fa = 0; fa < 4; fa++) {
#pragma unroll
    for (int fb = 0; fb < 2; fb++) {
      const int pl = wp3 * 32 + fb * 16 + lr;
      const int col = n0 + (pl & 31) + (pl >> 5) * NN;
#pragma unroll
      for (int j = 0; j < 4; j++) {
        const int c = wm3 * 64 + fa * 16 + lg * 4 + j;
        const size_t o = (size_t)c * HW2 + col;
        ob[o] = eacc[fa][fb][j] + x1b[o];
      }
    }
  }
}

extern "C" void kernel_launch(void* const* d_in, const int* in_sizes, int n_in,
                              void* d_out, int out_size, void* d_ws, size_t ws_size,
                              hipStream_t stream) {
  const float* x1 = (const float*)d_in[0];
  const float* x2 = (const float*)d_in[1];
  const float* wt = (const float*)d_in[2];
  const float* wp = (const float*)d_in[3];
  const float* wg = (const float*)d_in[4];
  const float* wm = (const float*)d_in[5];
  float* out = (float*)d_out;

  char* ws = (char*)d_ws;
  const size_t SZ_T = (size_t)NB * NN * CH * 2;
  u16* Tt = (u16*)ws; ws += SZ_T;
  u16* Pt = (u16*)ws; ws += SZ_T;
  u16* Gn = (u16*)ws; ws += SZ_T;
  float* denp = (float*)ws; ws += (size_t)NSLICE * NB * NN * 4;
  float* rdn = (float*)ws; ws += (size_t)NB * NN * 4;
  u16* wtb = (u16*)ws; ws += (size_t)CH * INTER2 * 2;
  u16* wpb = (u16*)ws; ws += (size_t)CH * INTER2 * 2;
  u16* wgb = (u16*)ws; ws += (size_t)CH * INTER2 * 2;
  u16* wmb = (u16*)ws; ws += (size_t)CH * INTER2 * 2;
  float* Yp = (float*)ws; ws += (size_t)NSK * NB * CH * NN * 4;
  if (ws_size < (size_t)(ws - (char*)d_ws)) return;

  hipLaunchKernelGGL(k_wcvt, dim3(32), dim3(256), 0, stream, wt, wp, wg, wm, wtb, wpb, wgb, wmb);
  hipLaunchKernelGGL(k_conv, dim3(144, NB, 2), dim3(256), 0, stream, x1, x2, wtb, wpb, wgb, Tt, Pt, Gn);
  hipLaunchKernelGGL(k_den, dim3(288, NB), dim3(256), 0, stream, Tt, Pt, denp);
  hipLaunchKernelGGL(k_rdn, dim3(72), dim3(256), 0, stream, denp, rdn);
  hipLaunchKernelGGL(k_att, dim3(864), dim3(256), 0, stream, Tt, Pt, Gn, rdn, Yp);
  hipLaunchKernelGGL(k_out, dim3(144, NB), dim3(256), 0, stream, Yp, wmb, x1, out);
}